// Round 3
// baseline (292.922 us; speedup 1.0000x reference)
//
#include <hip/hip_runtime.h>

typedef short short8 __attribute__((ext_vector_type(8)));
typedef float floatx4 __attribute__((ext_vector_type(4)));

#define C_DIM 512
#define KQ_STRIDE 1040   // bytes per LDS row: 512*2 + 16 pad (stride ≡ 4 mod 32 banks: 2-way = free)

__device__ __forceinline__ unsigned short f2bf(float f) {
    unsigned u = __builtin_bit_cast(unsigned, f);
    u = u + 0x7fffu + ((u >> 16) & 1u);
    return (unsigned short)(u >> 16);
}

// ---------------- pack kernel (grid 264):
// blocks 0..255   : keys/values -> MFMA B-fragment order
// blocks 256..263 : vnorm2[m] = sum(values[m]^2); block 256 tid 0 zeroes scal
// all blocks      : grid-stride copy keys/values -> out
// B frag (mfma 16x16x32): lane l holds B[k=(l>>4)*8+j][n=l&15]; index ((kt*32+NT)*64+l)*8+j
__global__ __launch_bounds__(256) void pack_kernel(
    const float* __restrict__ keys, const float* __restrict__ values,
    unsigned short* __restrict__ keysFrag, unsigned short* __restrict__ valsFrag,
    float* __restrict__ vnorm2,
    float* __restrict__ keysOut, float* __restrict__ valsOut,
    float* __restrict__ scal) {
    const int bx = blockIdx.x, tx = threadIdx.x;
    if (bx < 256) {
        int tid = bx * 256 + tx;
        int e  = tid & 32767;
        int l  = e & 63;
        int NT = (e >> 6) & 31;
        int kt = e >> 11;
        int li = l & 15, q4 = l >> 4;
        unsigned short tmp[8];
        if (tid < 32768) {
            const float* s = keys + (size_t)(NT * 16 + li) * C_DIM + kt * 32 + q4 * 8;
#pragma unroll
            for (int j = 0; j < 8; j++) tmp[j] = f2bf(s[j]);
            unsigned short* d = keysFrag + ((size_t)(kt * 32 + NT) * 64 + l) * 8;
            *(ushort4*)d       = make_ushort4(tmp[0], tmp[1], tmp[2], tmp[3]);
            *(ushort4*)(d + 4) = make_ushort4(tmp[4], tmp[5], tmp[6], tmp[7]);
        } else {
#pragma unroll
            for (int j = 0; j < 8; j++)
                tmp[j] = f2bf(values[(size_t)(kt * 32 + q4 * 8 + j) * C_DIM + NT * 16 + li]);
            unsigned short* d = valsFrag + ((size_t)(kt * 32 + NT) * 64 + l) * 8;
            *(ushort4*)d       = make_ushort4(tmp[0], tmp[1], tmp[2], tmp[3]);
            *(ushort4*)(d + 4) = make_ushort4(tmp[4], tmp[5], tmp[6], tmp[7]);
        }
    } else {
        int tid2 = (bx - 256) * 256 + tx;          // 0..2047
        int row = tid2 >> 2, seg = tid2 & 3;
        const float4* src = (const float4*)(values + (size_t)row * C_DIM + seg * 128);
        float ss = 0.f;
#pragma unroll
        for (int i = 0; i < 32; i++) {
            float4 v = src[i];
            ss += v.x * v.x + v.y * v.y + v.z * v.z + v.w * v.w;
        }
        ss += __shfl_xor(ss, 1, 64);
        ss += __shfl_xor(ss, 2, 64);
        if (seg == 0) vnorm2[row] = ss;
        if (bx == 256 && tx == 0) { scal[0] = 0.f; scal[1] = 0.f; scal[2] = 0.f; }
    }
    // grid-stride copy of keys/values to output (65536 float4 each, 67584 threads)
    int gtid = bx * 256 + tx;
    if (gtid < 65536) {
        ((float4*)keysOut)[gtid] = ((const float4*)keys)[gtid];
        ((float4*)valsOut)[gtid] = ((const float4*)values)[gtid];
    }
}

// ---------------- fused main kernel: 32 rows/block, 512 threads (8 waves), 1024 blocks
// wave tile: 32 rows x 64 cols for both GEMMs (cols [w*64, +64))
__global__ __launch_bounds__(512, 6) void fused_kernel(
    const float* __restrict__ key,
    const float* __restrict__ query,
    const unsigned short* __restrict__ keysFrag,
    const unsigned short* __restrict__ valsFrag,
    const float* __restrict__ values,
    const float* __restrict__ vnorm2,
    float* __restrict__ outRQ,
    float* __restrict__ scal) {   // [0]=entropy, [1]=gather, [2]=contrast
    __shared__ char kq[32 * KQ_STRIDE];      // raw-k bf16 tile, later p tile
    __shared__ float stats[8][32][5];        // [wave][row][m,z1,e1,z2,idx(int)]
    __shared__ float m1s[32], invks[32], invzs[32];
    __shared__ int   idxsh[32];
    __shared__ float gpart[8];

    const int tid = threadIdx.x;
    const int w  = tid >> 6;
    const int l  = tid & 63;
    const int li = l & 15;
    const int q4 = l >> 4;
    const int row0 = blockIdx.x << 5;

    // ---- P0: stream raw key -> bf16 LDS; ||k|| reduction in parallel ----
    {
        int r = (w << 2) + q4;                               // 16 lanes per row
        const float4* src = (const float4*)(key + (size_t)(row0 + r) * C_DIM);
        char* dstrow = kq + r * KQ_STRIDE;
        float ss = 0.f;
#pragma unroll
        for (int i = 0; i < 8; i++) {
            float4 v = src[i * 16 + li];
            *(ushort4*)(dstrow + i * 128 + li * 8) =
                make_ushort4(f2bf(v.x), f2bf(v.y), f2bf(v.z), f2bf(v.w));
            ss += v.x * v.x + v.y * v.y + v.z * v.z + v.w * v.w;
        }
#pragma unroll
        for (int m = 1; m < 16; m <<= 1) ss += __shfl_xor(ss, m, 64);
        if (li == 0) invks[r] = 1.0f / fmaxf(sqrtf(ss), 1e-12f);
    }
    __syncthreads();

    // ---- P1: score GEMM (raw), 32 rows x 64 cols, B prefetched one kt ahead ----
    floatx4 acc[8];                          // [rg*4+nt]
#pragma unroll
    for (int i = 0; i < 8; i++) acc[i] = (floatx4){0.f, 0.f, 0.f, 0.f};
    {
        const short8* kf = (const short8*)keysFrag;
        short8 bcur[4], bnxt[4];
#pragma unroll
        for (int nt = 0; nt < 4; nt++) bcur[nt] = kf[(size_t)((w * 4 + nt) * 64 + l)];
        for (int kt = 0; kt < 16; kt++) {
            if (kt < 15) {
#pragma unroll
                for (int nt = 0; nt < 4; nt++)
                    bnxt[nt] = kf[(size_t)(((kt + 1) * 32 + w * 4 + nt) * 64 + l)];
            }
            short8 a0 = *(const short8*)(kq + li * KQ_STRIDE + kt * 64 + q4 * 16);
            short8 a1 = *(const short8*)(kq + (16 + li) * KQ_STRIDE + kt * 64 + q4 * 16);
#pragma unroll
            for (int nt = 0; nt < 4; nt++) {
                acc[nt]     = __builtin_amdgcn_mfma_f32_16x16x32_bf16(a0, bcur[nt], acc[nt], 0, 0, 0);
                acc[4 + nt] = __builtin_amdgcn_mfma_f32_16x16x32_bf16(a1, bcur[nt], acc[4 + nt], 0, 0, 0);
            }
#pragma unroll
            for (int nt = 0; nt < 4; nt++) bcur[nt] = bnxt[nt];
        }
    }

    // ---- P2: per-row partial stats on s = acc * invk. C layout: col=li, row=q4*4+reg ----
#pragma unroll
    for (int rg = 0; rg < 2; rg++) {
#pragma unroll
        for (int reg = 0; reg < 4; reg++) {
            int rrow = rg * 16 + q4 * 4 + reg;
            float invk = invks[rrow];
            float s[4];
#pragma unroll
            for (int nt = 0; nt < 4; nt++) s[nt] = acc[rg * 4 + nt][reg] * invk;
            float m = s[0];
            int bi = w * 64 + li;
#pragma unroll
            for (int nt = 1; nt < 4; nt++)
                if (s[nt] > m) { m = s[nt]; bi = w * 64 + nt * 16 + li; }
            float z1 = 0.f, e1 = 0.f, z2 = 0.f;
#pragma unroll
            for (int nt = 0; nt < 4; nt++) {
                float p = __expf(s[nt] - m);
                z1 += p; e1 += p * s[nt]; z2 += p * p;
            }
#pragma unroll
            for (int msk = 1; msk < 16; msk <<= 1) {
                float mo  = __shfl_xor(m,  msk, 64);
                float z1o = __shfl_xor(z1, msk, 64);
                float e1o = __shfl_xor(e1, msk, 64);
                float z2o = __shfl_xor(z2, msk, 64);
                int   bio = __shfl_xor(bi, msk, 64);
                if (mo > m) {
                    float sc = __expf(m - mo);
                    z1 = z1 * sc + z1o; e1 = e1 * sc + e1o; z2 = z2 * sc * sc + z2o;
                    m = mo; bi = bio;
                } else if (mo == m) {
                    z1 += z1o; e1 += e1o; z2 += z2o; bi = min(bi, bio);
                } else {
                    float sc = __expf(mo - m);
                    z1 += z1o * sc; e1 += e1o * sc; z2 += z2o * sc * sc;
                }
            }
            if (li == 0) {
                float* st = stats[w][rrow];
                st[0] = m; st[1] = z1; st[2] = e1; st[3] = z2;
                ((int*)st)[4] = bi;
            }
        }
    }
    __syncthreads();

    // ---- combine across 8 waves (first 32 threads) ----
    if (tid < 32) {
        int r = tid;
        const float* st0 = stats[0][r];
        float m = st0[0], z1 = st0[1], e1 = st0[2], z2 = st0[3];
        int bi = ((const int*)st0)[4];
#pragma unroll
        for (int p = 1; p < 8; p++) {
            const float* st = stats[p][r];
            float mo = st[0], z1o = st[1], e1o = st[2], z2o = st[3];
            int bio = ((const int*)st)[4];
            if (mo > m) {
                float sc = __expf(m - mo);
                z1 = z1 * sc + z1o; e1 = e1 * sc + e1o; z2 = z2 * sc * sc + z2o;
                m = mo; bi = bio;
            } else if (mo == m) {
                z1 += z1o; e1 += e1o; z2 += z2o; bi = min(bi, bio);
            } else {
                float sc = __expf(mo - m);
                z1 += z1o * sc; e1 += e1o * sc; z2 += z2o * sc * sc;
            }
        }
        m1s[r] = m;
        invzs[r] = 1.0f / z1;
        idxsh[r] = bi;
        float ent = m + __logf(z1) - e1 / z1;   // logZ - E[s]
        float con = __logf(z2);                  // logsumexp(2s) - 2m
#pragma unroll
        for (int msk = 1; msk < 32; msk <<= 1) {
            ent += __shfl_xor(ent, msk, 64);
            con += __shfl_xor(con, msk, 64);
        }
        if (tid == 0) {
            atomicAdd(&scal[0], ent * (1.0f / 32768.0f));
            atomicAdd(&scal[2], con * (1.0f / 12800.0f));
        }
    }
    __syncthreads();

    // ---- P3: p = exp(s - m1) bf16, overwrite kq ----
#pragma unroll
    for (int rg = 0; rg < 2; rg++) {
#pragma unroll
        for (int reg = 0; reg < 4; reg++) {
            int rrow = rg * 16 + q4 * 4 + reg;
            float m1 = m1s[rrow];
            float invk = invks[rrow];
#pragma unroll
            for (int nt = 0; nt < 4; nt++) {
                float p = __expf(acc[rg * 4 + nt][reg] * invk - m1);
                int col = w * 64 + nt * 16 + li;
                *(unsigned short*)(kq + rrow * KQ_STRIDE + col * 2) = f2bf(p);
            }
        }
    }
    __syncthreads();

    // ---- P4: PV GEMM, 32 rows x out cols [w*64, +64) ----
#pragma unroll
    for (int i = 0; i < 8; i++) acc[i] = (floatx4){0.f, 0.f, 0.f, 0.f};
    {
        const short8* vf = (const short8*)valsFrag;
        short8 bcur[4], bnxt[4];
#pragma unroll
        for (int nt = 0; nt < 4; nt++) bcur[nt] = vf[(size_t)((w * 4 + nt) * 64 + l)];
        for (int kt = 0; kt < 16; kt++) {
            if (kt < 15) {
#pragma unroll
                for (int nt = 0; nt < 4; nt++)
                    bnxt[nt] = vf[(size_t)(((kt + 1) * 32 + w * 4 + nt) * 64 + l)];
            }
            short8 a0 = *(const short8*)(kq + li * KQ_STRIDE + kt * 64 + q4 * 16);
            short8 a1 = *(const short8*)(kq + (16 + li) * KQ_STRIDE + kt * 64 + q4 * 16);
#pragma unroll
            for (int nt = 0; nt < 4; nt++) {
                acc[nt]     = __builtin_amdgcn_mfma_f32_16x16x32_bf16(a0, bcur[nt], acc[nt], 0, 0, 0);
                acc[4 + nt] = __builtin_amdgcn_mfma_f32_16x16x32_bf16(a1, bcur[nt], acc[4 + nt], 0, 0, 0);
            }
#pragma unroll
            for (int nt = 0; nt < 4; nt++) bcur[nt] = bnxt[nt];
        }
    }

    // ---- P5: scale by 1/Z1 and store ----
#pragma unroll
    for (int rg = 0; rg < 2; rg++) {
#pragma unroll
        for (int reg = 0; reg < 4; reg++) {
            int rrow = rg * 16 + q4 * 4 + reg;
            float iz = invzs[rrow];
            float* orow = outRQ + (size_t)(row0 + rrow) * C_DIM + w * 64 + li;
#pragma unroll
            for (int nt = 0; nt < 4; nt++) orow[nt * 16] = acc[rg * 4 + nt][reg] * iz;
        }
    }

    // ---- P6: gather loss, algebraic: ||q^-v||^2 = 1 + ||v||^2 - 2 (q.v)/||q|| ----
    {
        int r = (w << 2) + q4;
        int mi = idxsh[r];
        const float4* qr = (const float4*)(query + (size_t)(row0 + r) * C_DIM);
        const float4* vr = (const float4*)(values + (size_t)mi * C_DIM);
        float ssq = 0.f, dqv = 0.f;
#pragma unroll
        for (int i = 0; i < 8; i++) {
            float4 a = qr[i * 16 + li];
            float4 b = vr[i * 16 + li];
            ssq += a.x * a.x + a.y * a.y + a.z * a.z + a.w * a.w;
            dqv += a.x * b.x + a.y * b.y + a.z * b.z + a.w * b.w;
        }
#pragma unroll
        for (int m = 1; m < 16; m <<= 1) {
            ssq += __shfl_xor(ssq, m, 64);
            dqv += __shfl_xor(dqv, m, 64);
        }
        float g = 1.0f + vnorm2[mi] - 2.0f * dqv / fmaxf(sqrtf(ssq), 1e-12f);
        float gl = (li == 0) ? g : 0.f;
        gl += __shfl_xor(gl, 16, 64);
        gl += __shfl_xor(gl, 32, 64);
        if (l == 0) gpart[w] = gl;
    }
    __syncthreads();
    if (tid == 0) {
        float s = 0.f;
#pragma unroll
        for (int i = 0; i < 8; i++) s += gpart[i];
        atomicAdd(&scal[1], s * (1.0f / (32768.0f * 512.0f)));
    }
}

extern "C" void kernel_launch(void* const* d_in, const int* in_sizes, int n_in,
                              void* d_out, int out_size, void* d_ws, size_t ws_size,
                              hipStream_t stream) {
    (void)in_sizes; (void)n_in; (void)out_size; (void)ws_size;
    const float* key    = (const float*)d_in[0];
    const float* query  = (const float*)d_in[1];
    const float* keysIn = (const float*)d_in[2];
    const float* valsIn = (const float*)d_in[3];
    float* out = (float*)d_out;

    unsigned short* keysFrag = (unsigned short*)d_ws;            // 512 KB
    unsigned short* valsFrag = keysFrag + 512 * 512;             // 512 KB
    float* vnorm2 = (float*)(valsFrag + 512 * 512);              // 2 KB

    float* outRQ   = out;                       // 16777216 floats
    float* scal    = out + 16777216;            // entropy, gathering, contrast
    float* keysOut = out + 16777219;            // 262144 floats
    float* valsOut = keysOut + 262144;          // 262144 floats

    pack_kernel<<<264, 256, 0, stream>>>(keysIn, valsIn, keysFrag, valsFrag,
                                         vnorm2, keysOut, valsOut, scal);
    fused_kernel<<<1024, 512, 0, stream>>>(key, query, keysFrag, valsFrag,
                                           valsIn, vnorm2, outRQ, scal);
}

// Round 4
// 249.338 us; speedup vs baseline: 1.1748x; 1.1748x over previous
//
#include <hip/hip_runtime.h>

typedef short short8 __attribute__((ext_vector_type(8)));
typedef float floatx4 __attribute__((ext_vector_type(4)));

#define C_DIM 512
#define KQ_STRIDE 1040   // bytes per LDS row: 512*2 + 16 pad

__device__ __forceinline__ unsigned short f2bf(float f) {
    unsigned u = __builtin_bit_cast(unsigned, f);
    u = u + 0x7fffu + ((u >> 16) & 1u);
    return (unsigned short)(u >> 16);
}

// ---------------- pack kernel (grid 264):
// blocks 0..255   : keys/values -> MFMA B-fragment order
// blocks 256..263 : vnorm2[m] = sum(values[m]^2); block 256 tid 0 zeroes scal
// all blocks      : grid-stride copy keys/values -> out
__global__ __launch_bounds__(256) void pack_kernel(
    const float* __restrict__ keys, const float* __restrict__ values,
    unsigned short* __restrict__ keysFrag, unsigned short* __restrict__ valsFrag,
    float* __restrict__ vnorm2,
    float* __restrict__ keysOut, float* __restrict__ valsOut,
    float* __restrict__ scal) {
    const int bx = blockIdx.x, tx = threadIdx.x;
    if (bx < 256) {
        int tid = bx * 256 + tx;
        int e  = tid & 32767;
        int l  = e & 63;
        int NT = (e >> 6) & 31;
        int kt = e >> 11;
        int li = l & 15, q4 = l >> 4;
        unsigned short tmp[8];
        if (tid < 32768) {
            const float* s = keys + (size_t)(NT * 16 + li) * C_DIM + kt * 32 + q4 * 8;
#pragma unroll
            for (int j = 0; j < 8; j++) tmp[j] = f2bf(s[j]);
            unsigned short* d = keysFrag + ((size_t)(kt * 32 + NT) * 64 + l) * 8;
            *(ushort4*)d       = make_ushort4(tmp[0], tmp[1], tmp[2], tmp[3]);
            *(ushort4*)(d + 4) = make_ushort4(tmp[4], tmp[5], tmp[6], tmp[7]);
        } else {
#pragma unroll
            for (int j = 0; j < 8; j++)
                tmp[j] = f2bf(values[(size_t)(kt * 32 + q4 * 8 + j) * C_DIM + NT * 16 + li]);
            unsigned short* d = valsFrag + ((size_t)(kt * 32 + NT) * 64 + l) * 8;
            *(ushort4*)d       = make_ushort4(tmp[0], tmp[1], tmp[2], tmp[3]);
            *(ushort4*)(d + 4) = make_ushort4(tmp[4], tmp[5], tmp[6], tmp[7]);
        }
    } else {
        int tid2 = (bx - 256) * 256 + tx;          // 0..2047
        int row = tid2 >> 2, seg = tid2 & 3;
        const float4* src = (const float4*)(values + (size_t)row * C_DIM + seg * 128);
        float ss = 0.f;
#pragma unroll
        for (int i = 0; i < 32; i++) {
            float4 v = src[i];
            ss += v.x * v.x + v.y * v.y + v.z * v.z + v.w * v.w;
        }
        ss += __shfl_xor(ss, 1, 64);
        ss += __shfl_xor(ss, 2, 64);
        if (seg == 0) vnorm2[row] = ss;
        if (bx == 256 && tx == 0) { scal[0] = 0.f; scal[1] = 0.f; scal[2] = 0.f; }
    }
    int gtid = bx * 256 + tx;
    if (gtid < 65536) {
        ((float4*)keysOut)[gtid] = ((const float4*)keys)[gtid];
        ((float4*)valsOut)[gtid] = ((const float4*)values)[gtid];
    }
}

// ---------------- fused main kernel: 64 rows/block, 512 threads (8 waves), 512 blocks
// wave tile: 64 rows x 64 cols for both GEMMs (cols [w*64, +64))
__global__ __launch_bounds__(512, 4) void fused_kernel(
    const float* __restrict__ key,
    const float* __restrict__ query,
    const unsigned short* __restrict__ keysFrag,
    const unsigned short* __restrict__ valsFrag,
    const float* __restrict__ values,
    const float* __restrict__ vnorm2,
    float* __restrict__ outRQ,
    float* __restrict__ scal) {   // [0]=entropy, [1]=gather, [2]=contrast
    __shared__ char kq[64 * KQ_STRIDE];      // raw-k bf16 tile, later p tile
    __shared__ float stats[8][65][5];        // [wave][row(+pad)][m,z1,e1,z2,idx(int)]
    __shared__ float m1s[64], invks[64], invzs[64];
    __shared__ int   idxsh[64];
    __shared__ float epart[8][2];            // per-wave [ent, con]
    __shared__ float gpart[8];

    const int tid = threadIdx.x;
    const int w  = tid >> 6;
    const int l  = tid & 63;
    const int li = l & 15;
    const int q4 = l >> 4;
    const int row0 = blockIdx.x << 6;

    const short8* kf = (const short8*)keysFrag;
    const short8* vf = (const short8*)valsFrag;

    // ---- P0: stream raw key -> bf16 LDS; ||k|| reduction in parallel ----
#pragma unroll
    for (int it = 0; it < 2; it++) {
        int r = (w << 3) + (it << 2) + q4;                   // 16 lanes per row
        const float4* src = (const float4*)(key + (size_t)(row0 + r) * C_DIM);
        char* dstrow = kq + r * KQ_STRIDE;
        float ss = 0.f;
#pragma unroll
        for (int i = 0; i < 8; i++) {
            float4 v = src[i * 16 + li];
            *(ushort4*)(dstrow + i * 128 + li * 8) =
                make_ushort4(f2bf(v.x), f2bf(v.y), f2bf(v.z), f2bf(v.w));
            ss += v.x * v.x + v.y * v.y + v.z * v.z + v.w * v.w;
        }
#pragma unroll
        for (int m = 1; m < 16; m <<= 1) ss += __shfl_xor(ss, m, 64);
        if (li == 0) invks[r] = 1.0f / fmaxf(sqrtf(ss), 1e-12f);
    }
    // prefetch first score-B fragments BEFORE the barrier (independent of LDS)
    short8 bcur[4], bnxt[4];
#pragma unroll
    for (int nt = 0; nt < 4; nt++) bcur[nt] = kf[(size_t)((w * 4 + nt) * 64 + l)];
    __syncthreads();

    // ---- P1: score GEMM (raw k), 64 rows x cols [w*64, +64) ----
    floatx4 acc[16];                         // [rg*4+nt]
#pragma unroll
    for (int i = 0; i < 16; i++) acc[i] = (floatx4){0.f, 0.f, 0.f, 0.f};
    for (int kt = 0; kt < 16; kt++) {
        if (kt < 15) {
#pragma unroll
            for (int nt = 0; nt < 4; nt++)
                bnxt[nt] = kf[(size_t)(((kt + 1) * 32 + w * 4 + nt) * 64 + l)];
        }
        short8 a[4];
#pragma unroll
        for (int rg = 0; rg < 4; rg++)
            a[rg] = *(const short8*)(kq + (rg * 16 + li) * KQ_STRIDE + kt * 64 + q4 * 16);
#pragma unroll
        for (int rg = 0; rg < 4; rg++)
#pragma unroll
            for (int nt = 0; nt < 4; nt++)
                acc[rg * 4 + nt] = __builtin_amdgcn_mfma_f32_16x16x32_bf16(
                    a[rg], bcur[nt], acc[rg * 4 + nt], 0, 0, 0);
#pragma unroll
        for (int nt = 0; nt < 4; nt++) bcur[nt] = bnxt[nt];
    }

    // ---- P2: per-row partial stats on s = acc * invk. C layout: col=li, row=q4*4+reg ----
#pragma unroll
    for (int rg = 0; rg < 4; rg++) {
#pragma unroll
        for (int reg = 0; reg < 4; reg++) {
            int rrow = rg * 16 + q4 * 4 + reg;
            float invk = invks[rrow];
            float s[4];
#pragma unroll
            for (int nt = 0; nt < 4; nt++) s[nt] = acc[rg * 4 + nt][reg] * invk;
            float m = s[0];
            int bi = w * 64 + li;
#pragma unroll
            for (int nt = 1; nt < 4; nt++)
                if (s[nt] > m) { m = s[nt]; bi = w * 64 + nt * 16 + li; }
            float z1 = 0.f, e1 = 0.f, z2 = 0.f;
#pragma unroll
            for (int nt = 0; nt < 4; nt++) {
                float p = __expf(s[nt] - m);
                z1 += p; e1 += p * s[nt]; z2 += p * p;
            }
#pragma unroll
            for (int msk = 1; msk < 16; msk <<= 1) {
                float mo  = __shfl_xor(m,  msk, 64);
                float z1o = __shfl_xor(z1, msk, 64);
                float e1o = __shfl_xor(e1, msk, 64);
                float z2o = __shfl_xor(z2, msk, 64);
                int   bio = __shfl_xor(bi, msk, 64);
                if (mo > m) {
                    float sc = __expf(m - mo);
                    z1 = z1 * sc + z1o; e1 = e1 * sc + e1o; z2 = z2 * sc * sc + z2o;
                    m = mo; bi = bio;
                } else if (mo == m) {
                    z1 += z1o; e1 += e1o; z2 += z2o; bi = min(bi, bio);
                } else {
                    float sc = __expf(mo - m);
                    z1 += z1o * sc; e1 += e1o * sc; z2 += z2o * sc * sc;
                }
            }
            if (li == 0) {
                float* st = stats[w][rrow];
                st[0] = m; st[1] = z1; st[2] = e1; st[3] = z2;
                ((int*)st)[4] = bi;
            }
        }
    }
    __syncthreads();

    // ---- distributed combine: thread -> (row=tid>>3, part=tid&7), 3-step butterfly ----
    {
        int r = tid >> 3, p = tid & 7;
        const float* st = stats[p][r];
        float m = st[0], z1 = st[1], e1 = st[2], z2 = st[3];
        int bi = ((const int*)st)[4];
#pragma unroll
        for (int msk = 1; msk < 8; msk <<= 1) {
            float mo  = __shfl_xor(m,  msk, 64);
            float z1o = __shfl_xor(z1, msk, 64);
            float e1o = __shfl_xor(e1, msk, 64);
            float z2o = __shfl_xor(z2, msk, 64);
            int   bio = __shfl_xor(bi, msk, 64);
            if (mo > m) {
                float sc = __expf(m - mo);
                z1 = z1 * sc + z1o; e1 = e1 * sc + e1o; z2 = z2 * sc * sc + z2o;
                m = mo; bi = bio;
            } else if (mo == m) {
                z1 += z1o; e1 += e1o; z2 += z2o; bi = min(bi, bio);
            } else {
                float sc = __expf(mo - m);
                z1 += z1o * sc; e1 += e1o * sc; z2 += z2o * sc * sc;
            }
        }
        float ent = 0.f, con = 0.f;
        if (p == 0) {
            m1s[r] = m;
            invzs[r] = 1.0f / z1;
            idxsh[r] = bi;
            ent = m + __logf(z1) - e1 / z1;   // logZ - E[s]
            con = __logf(z2);                  // logsumexp(2s) - 2m
        }
#pragma unroll
        for (int msk = 8; msk < 64; msk <<= 1) {
            ent += __shfl_xor(ent, msk, 64);
            con += __shfl_xor(con, msk, 64);
        }
        if (l == 0) { epart[w][0] = ent; epart[w][1] = con; }
    }
    __syncthreads();

    // ---- P3: prefetch PV-B fragments, then p = exp(s - m1) bf16 overwrite kq ----
#pragma unroll
    for (int nt = 0; nt < 4; nt++) bcur[nt] = vf[(size_t)((w * 4 + nt) * 64 + l)];
#pragma unroll
    for (int rg = 0; rg < 4; rg++) {
#pragma unroll
        for (int reg = 0; reg < 4; reg++) {
            int rrow = rg * 16 + q4 * 4 + reg;
            float m1 = m1s[rrow];
            float invk = invks[rrow];
#pragma unroll
            for (int nt = 0; nt < 4; nt++) {
                float p = __expf(acc[rg * 4 + nt][reg] * invk - m1);
                int col = w * 64 + nt * 16 + li;
                *(unsigned short*)(kq + rrow * KQ_STRIDE + col * 2) = f2bf(p);
            }
        }
    }
    __syncthreads();

    // ---- P4: PV GEMM, 64 rows x out cols [w*64, +64) ----
#pragma unroll
    for (int i = 0; i < 16; i++) acc[i] = (floatx4){0.f, 0.f, 0.f, 0.f};
    for (int kt = 0; kt < 16; kt++) {
        if (kt < 15) {
#pragma unroll
            for (int nt = 0; nt < 4; nt++)
                bnxt[nt] = vf[(size_t)(((kt + 1) * 32 + w * 4 + nt) * 64 + l)];
        }
        short8 a[4];
#pragma unroll
        for (int rg = 0; rg < 4; rg++)
            a[rg] = *(const short8*)(kq + (rg * 16 + li) * KQ_STRIDE + kt * 64 + q4 * 16);
#pragma unroll
        for (int rg = 0; rg < 4; rg++)
#pragma unroll
            for (int nt = 0; nt < 4; nt++)
                acc[rg * 4 + nt] = __builtin_amdgcn_mfma_f32_16x16x32_bf16(
                    a[rg], bcur[nt], acc[rg * 4 + nt], 0, 0, 0);
#pragma unroll
        for (int nt = 0; nt < 4; nt++) bcur[nt] = bnxt[nt];
    }

    // ---- P5: scale by 1/Z1 and store ----
#pragma unroll
    for (int rg = 0; rg < 4; rg++) {
#pragma unroll
        for (int reg = 0; reg < 4; reg++) {
            int rrow = rg * 16 + q4 * 4 + reg;
            float iz = invzs[rrow];
            float* orow = outRQ + (size_t)(row0 + rrow) * C_DIM + w * 64 + li;
#pragma unroll
            for (int nt = 0; nt < 4; nt++) orow[nt * 16] = acc[rg * 4 + nt][reg] * iz;
        }
    }

    // ---- P6: gather loss, algebraic: ||q^-v||^2 = 1 + ||v||^2 - 2 (q.v)/||q|| ----
    {
        float gl = 0.f;
#pragma unroll
        for (int it = 0; it < 2; it++) {
            int r = (w << 3) + (it << 2) + q4;
            int mi = idxsh[r];
            const float4* qr = (const float4*)(query + (size_t)(row0 + r) * C_DIM);
            const float4* vr = (const float4*)(values + (size_t)mi * C_DIM);
            float ssq = 0.f, dqv = 0.f;
#pragma unroll
            for (int i = 0; i < 8; i++) {
                float4 a = qr[i * 16 + li];
                float4 b = vr[i * 16 + li];
                ssq += a.x * a.x + a.y * a.y + a.z * a.z + a.w * a.w;
                dqv += a.x * b.x + a.y * b.y + a.z * b.z + a.w * b.w;
            }
#pragma unroll
            for (int m = 1; m < 16; m <<= 1) {
                ssq += __shfl_xor(ssq, m, 64);
                dqv += __shfl_xor(dqv, m, 64);
            }
            float g = 1.0f + vnorm2[mi] - 2.0f * dqv / fmaxf(sqrtf(ssq), 1e-12f);
            gl += (li == 0) ? g : 0.f;
        }
        gl += __shfl_xor(gl, 16, 64);
        gl += __shfl_xor(gl, 32, 64);
        if (l == 0) gpart[w] = gl;
    }
    __syncthreads();
    if (tid == 0) {
        float gs = 0.f, es = 0.f, cs = 0.f;
#pragma unroll
        for (int i = 0; i < 8; i++) {
            gs += gpart[i]; es += epart[i][0]; cs += epart[i][1];
        }
        atomicAdd(&scal[0], es * (1.0f / 32768.0f));
        atomicAdd(&scal[1], gs * (1.0f / (32768.0f * 512.0f)));
        atomicAdd(&scal[2], cs * (1.0f / 12800.0f));
    }
}

extern "C" void kernel_launch(void* const* d_in, const int* in_sizes, int n_in,
                              void* d_out, int out_size, void* d_ws, size_t ws_size,
                              hipStream_t stream) {
    (void)in_sizes; (void)n_in; (void)out_size; (void)ws_size;
    const float* key    = (const float*)d_in[0];
    const float* query  = (const float*)d_in[1];
    const float* keysIn = (const float*)d_in[2];
    const float* valsIn = (const float*)d_in[3];
    float* out = (float*)d_out;

    unsigned short* keysFrag = (unsigned short*)d_ws;            // 512 KB
    unsigned short* valsFrag = keysFrag + 512 * 512;             // 512 KB
    float* vnorm2 = (float*)(valsFrag + 512 * 512);              // 2 KB

    float* outRQ   = out;                       // 16777216 floats
    float* scal    = out + 16777216;            // entropy, gathering, contrast
    float* keysOut = out + 16777219;            // 262144 floats
    float* valsOut = keysOut + 262144;          // 262144 floats

    pack_kernel<<<264, 256, 0, stream>>>(keysIn, valsIn, keysFrag, valsFrag,
                                         vnorm2, keysOut, valsOut, scal);
    fused_kernel<<<512, 512, 0, stream>>>(key, query, keysFrag, valsFrag,
                                          valsIn, vnorm2, outRQ, scal);
}